// Round 3
// baseline (98.449 us; speedup 1.0000x reference)
//
#include <hip/hip_runtime.h>

// Reck-mesh MZI layer, N=256, BATCH=4096.
// out[b][i] = sum_j x[b][j] * Re(e^{i phi_ext[i]} U[i][j])
// Wavefront schedule t = 2L + p (depth 509, padded 512): ops at equal t touch
// disjoint row pairs. One wave per column; lane l holds rows 4l..4l+3.
// Coefficients pre-reordered into a (t,lane) stream with identities baked in,
// staged global->LDS via global_load_lds (async, un-sinkable), double-buffered.

#define NN 256
#define NB 4096
#define TSTRIDE 192                 // float4 per step in the table: 3 slots * 64 lanes
#define WS_WT_OFF (528 * 192 * 16)  // table covers t < 528; Wt[256][256] after it

// ---------------- coefficient stream ----------------
// slot A: p = 4l (+1 if t odd);  slot B: p = A+2;  slot C (odd t): p = 4l-1
// (slot C = lane l-1's slot B, pre-shifted so the hot loop needs no coeff shuffle)
__global__ __launch_bounds__(64) void coeff2_kernel(const float* __restrict__ theta,
                                                    const float* __restrict__ phi,
                                                    float4* __restrict__ cf2) {
    const int t = blockIdx.x;
    const int l = threadIdx.x;
    const int pA = (t & 1) ? (4 * l + 1) : (4 * l);
    const int ps[3] = {pA, pA + 2, (t & 1) ? (4 * l - 1) : -1};
#pragma unroll
    for (int s = 0; s < 3; ++s) {
        int p = ps[s];
        float4 v = make_float4(1.f, 0.f, 0.f, 0.f);  // identity rotation
        if (p >= 0 && p <= t && p + t <= 508) {      // active op at (t,p)
            int L = (t - p) >> 1;                    // layer 0..254
            int k = ((L * (511 - L)) >> 1) + p;      // off(L) = L*(511-L)/2
            float sc, cc, sp, cp;
            __sincosf(theta[k], &sc, &cc);
            __sincosf(phi[k], &sp, &cp);
            v = make_float4(cc, sc * cp, sc * sp, 0.f);
        }
        cf2[t * TSTRIDE + s * 64 + l] = v;
    }
}

// ---------------- build U columns ----------------
__device__ __forceinline__ float dpp_up1(float x) {   // lane i <- lane i-1, lane0 -> 0
    int r = __builtin_amdgcn_update_dpp(0, __builtin_bit_cast(int, x), 0x138, 0xF, 0xF, true);
    return __builtin_bit_cast(float, r);
}
__device__ __forceinline__ float dpp_dn1(float x) {   // lane i <- lane i+1, lane63 -> 0
    int r = __builtin_amdgcn_update_dpp(0, __builtin_bit_cast(int, x), 0x130, 0xF, 0xF, true);
    return __builtin_bit_cast(float, r);
}

__device__ __forceinline__ void rot2(float& ar, float& ai, float& br, float& bi, float4 co) {
    float c = co.x, sx = co.y, sy = co.z;
    float nar = c * ar - (sx * br + sy * bi);
    float nai = c * ai - (sx * bi - sy * br);
    float nbr = sx * ar - sy * ai + c * br;
    float nbi = sx * ai + sy * ar + c * bi;
    ar = nar; ai = nai; br = nbr; bi = nbi;
}

// async global->LDS, 16B per lane; LDS dest = wave-uniform base + lane*16
__device__ __forceinline__ void glds16(const float4* g, float4* l) {
    __builtin_amdgcn_global_load_lds((const __attribute__((address_space(1))) void*)g,
                                     (__attribute__((address_space(3))) void*)l,
                                     16, 0, 0);
}

__global__ __launch_bounds__(64, 1) void build_kernel(const float4* __restrict__ cf2,
                                                      const float* __restrict__ phi_ext,
                                                      float* __restrict__ Wt) {
    // 20 float4-slots/group (8 A, 8 B, 4 C), double-buffered: 2 * 20KB LDS
    __shared__ float4 sbuf0[20 * 64];
    __shared__ float4 sbuf1[20 * 64];

    const int j = blockIdx.x;   // column of U
    const int l = threadIdx.x;  // lane
    const int r0 = 4 * l;

    float ur0 = (r0 + 0 == j) ? 1.f : 0.f, ui0 = 0.f;
    float ur1 = (r0 + 1 == j) ? 1.f : 0.f, ui1 = 0.f;
    float ur2 = (r0 + 2 == j) ? 1.f : 0.f, ui2 = 0.f;
    float ur3 = (r0 + 3 == j) ? 1.f : 0.f, ui3 = 0.f;

    // stage group g (8 steps): A_jj -> slot jj, B_jj -> 8+jj, C(odd jj) -> 16+(jj>>1)
    auto stage = [&](int g, float4* buf) {
        const float4* gp = cf2 + (size_t)g * (8 * TSTRIDE) + l;
#pragma unroll
        for (int jj = 0; jj < 8; ++jj) {
            glds16(gp + jj * TSTRIDE,      buf + jj * 64);
            glds16(gp + jj * TSTRIDE + 64, buf + (8 + jj) * 64);
        }
#pragma unroll
        for (int c = 0; c < 4; ++c)
            glds16(gp + (2 * c + 1) * TSTRIDE + 128, buf + (16 + c) * 64);
    };

    auto compute = [&](const float4* buf) {
        float4 A[8], B[8], C[4];
#pragma unroll
        for (int jj = 0; jj < 8; ++jj) {
            A[jj] = buf[jj * 64 + l];
            B[jj] = buf[(8 + jj) * 64 + l];
        }
#pragma unroll
        for (int c = 0; c < 4; ++c) C[c] = buf[(16 + c) * 64 + l];

#pragma unroll
        for (int jj = 0; jj < 8; ++jj) {
            if ((jj & 1) == 0) {
                // even step: p=4l (rows 4l,4l+1), p=4l+2 (rows 4l+2,4l+3), intra-lane
                rot2(ur0, ui0, ur1, ui1, A[jj]);
                rot2(ur2, ui2, ur3, ui3, B[jj]);
            } else {
                // DPP reads pre-step neighbor state (lockstep, before any write)
                float d0r = dpp_dn1(ur0), d0i = dpp_dn1(ui0);  // lane l+1's row 4l+4
                float u3r = dpp_up1(ur3), u3i = dpp_up1(ui3);  // lane l-1's row 4l-1
                // p = 4l+1: rows 4l+1,4l+2 intra-lane
                rot2(ur1, ui1, ur2, ui2, A[jj]);
                // p = 4l+3: upper row here; partner from lane l+1 (lane63: B=identity)
                float4 cb = B[jj];
                float n3r = cb.x * ur3 - (cb.y * d0r + cb.z * d0i);
                float n3i = cb.x * ui3 - (cb.y * d0i - cb.z * d0r);
                // p = 4l-1: lower row here; upper from lane l-1 (lane0: C=identity)
                float4 cc = C[jj >> 1];
                float n0r = cc.y * u3r - cc.z * u3i + cc.x * ur0;
                float n0i = cc.y * u3i + cc.z * u3r + cc.x * ui0;
                ur3 = n3r; ui3 = n3i; ur0 = n0r; ui0 = n0i;
            }
        }
    };

    stage(0, sbuf0);
    asm volatile("s_waitcnt vmcnt(0)" ::: "memory");
    for (int g = 0; g < 64; g += 2) {       // 64 groups x 8 steps = 512 steps
        stage(g + 1, sbuf1);                 // in flight while computing sbuf0
        compute(sbuf0);                      // ds_reads consumed before overwrite below
        asm volatile("s_waitcnt vmcnt(0) lgkmcnt(0)" ::: "memory");
        stage(g + 2, sbuf0);                 // max staged g=64 -> t<=519 < 528 (pad)
        compute(sbuf1);
        asm volatile("s_waitcnt vmcnt(0) lgkmcnt(0)" ::: "memory");
    }

    // phase screen + real part; store transposed (Wt[j][i]) for coalesced GEMM reads
    float4 pe = *(const float4*)(phi_ext + r0);
    float s0, c0s, s1, c1s, s2, c2s, s3, c3s;
    __sincosf(pe.x, &s0, &c0s);
    __sincosf(pe.y, &s1, &c1s);
    __sincosf(pe.z, &s2, &c2s);
    __sincosf(pe.w, &s3, &c3s);
    float w0 = c0s * ur0 - s0 * ui0;
    float w1 = c1s * ur1 - s1 * ui1;
    float w2 = c2s * ur2 - s2 * ui2;
    float w3 = c3s * ur3 - s3 * ui3;
    *(float4*)(Wt + j * NN + r0) = make_float4(w0, w1, w2, w3);
}

// ---------------- out = x @ Wt (fp32; no fp32 MFMA on CDNA4) ----------------
__global__ __launch_bounds__(256) void gemm_kernel(const float* __restrict__ x,
                                                   const float* __restrict__ Wt,
                                                   float* __restrict__ out) {
    __shared__ float Xs[64][36];
    __shared__ float Bs[32][68];

    const int tid = threadIdx.x;
    const int b0 = blockIdx.x * 64;
    const int i0 = blockIdx.y * 64;
    const int tx = tid & 15;
    const int ty = tid >> 4;

    const int xr = tid >> 3;
    const int xc = (tid & 7) * 4;
    const int bk = tid >> 4;
    const int bc = (tid & 15) * 4;

    float acc[4][4] = {};

    for (int k0 = 0; k0 < NN; k0 += 32) {
        float4 g0 = *(const float4*)(x + (b0 + xr) * NN + k0 + xc);
        float4 g1 = *(const float4*)(x + (b0 + xr + 32) * NN + k0 + xc);
        float4 w0 = *(const float4*)(Wt + (k0 + bk) * NN + i0 + bc);
        float4 w1 = *(const float4*)(Wt + (k0 + bk + 16) * NN + i0 + bc);
        *(float4*)&Xs[xr][xc]      = g0;
        *(float4*)&Xs[xr + 32][xc] = g1;
        *(float4*)&Bs[bk][bc]      = w0;
        *(float4*)&Bs[bk + 16][bc] = w1;
        __syncthreads();

#pragma unroll 8
        for (int k = 0; k < 32; ++k) {
            float4 bv = *(const float4*)&Bs[k][tx * 4];
            float x0 = Xs[ty * 4 + 0][k];
            float x1 = Xs[ty * 4 + 1][k];
            float x2 = Xs[ty * 4 + 2][k];
            float x3 = Xs[ty * 4 + 3][k];
            acc[0][0] += x0 * bv.x; acc[0][1] += x0 * bv.y; acc[0][2] += x0 * bv.z; acc[0][3] += x0 * bv.w;
            acc[1][0] += x1 * bv.x; acc[1][1] += x1 * bv.y; acc[1][2] += x1 * bv.z; acc[1][3] += x1 * bv.w;
            acc[2][0] += x2 * bv.x; acc[2][1] += x2 * bv.y; acc[2][2] += x2 * bv.z; acc[2][3] += x2 * bv.w;
            acc[3][0] += x3 * bv.x; acc[3][1] += x3 * bv.y; acc[3][2] += x3 * bv.z; acc[3][3] += x3 * bv.w;
        }
        __syncthreads();
    }

#pragma unroll
    for (int mm = 0; mm < 4; ++mm) {
        *(float4*)(out + (b0 + ty * 4 + mm) * NN + i0 + tx * 4) =
            make_float4(acc[mm][0], acc[mm][1], acc[mm][2], acc[mm][3]);
    }
}

extern "C" void kernel_launch(void* const* d_in, const int* in_sizes, int n_in,
                              void* d_out, int out_size, void* d_ws, size_t ws_size,
                              hipStream_t stream) {
    const float* x     = (const float*)d_in[0];
    const float* theta = (const float*)d_in[1];
    const float* phi_i = (const float*)d_in[2];
    const float* phi_e = (const float*)d_in[3];
    float* out = (float*)d_out;

    float4* cf2 = (float4*)d_ws;                       // 528*192*16 = 1,622,016 B
    float*  Wt  = (float*)((char*)d_ws + WS_WT_OFF);   // 256*256*4  =   262,144 B

    coeff2_kernel<<<dim3(528), dim3(64), 0, stream>>>(theta, phi_i, cf2);
    build_kernel<<<dim3(NN), dim3(64), 0, stream>>>(cf2, phi_e, Wt);
    gemm_kernel<<<dim3(NB / 64, NN / 64), dim3(256), 0, stream>>>(x, Wt, out);
}

// Round 5
// 76.763 us; speedup vs baseline: 1.2825x; 1.2825x over previous
//
#include <hip/hip_runtime.h>

// Reck-mesh MZI layer, N=256, BATCH=4096.
// out[b][i] = sum_j x[b][j] * Re(e^{i phi_ext[i]} U[i][j])
// Wavefront schedule t = 2L + p (depth 509, padded 512): ops at equal t touch
// disjoint row pairs. One consumer wave per column; lane l holds rows 4l..4l+3.
// Block = 2 waves: wave1 = producer streaming coefficients global->LDS ring
// (K=3 groups); wave0 = consumer computing from LDS only. Barrier per group.

#define NN 256
#define NB 4096
// table: 64 groups x 16 slots x 64 lanes x 16B = 1,048,576 B
#define WS_WT_OFF 1048576           // Wt[256][256] after the table

typedef float f32x4 __attribute__((ext_vector_type(4)));

// ---------------- coefficient stream ----------------
// t = 8g + jj. slot A_jj = jj (p = 4l, +1 if t odd), slot B_jj = 8+jj (p = A+2).
// Identity (1,0,0) baked in for inactive ops.
__global__ __launch_bounds__(64) void coeff2_kernel(const float* __restrict__ theta,
                                                    const float* __restrict__ phi,
                                                    f32x4* __restrict__ cf3) {
    const int t = blockIdx.x;        // 0..511
    const int l = threadIdx.x;
    const int g = t >> 3, jj = t & 7;
    const int pA = (t & 1) ? (4 * l + 1) : (4 * l);
#pragma unroll
    for (int s = 0; s < 2; ++s) {
        int p = pA + 2 * s;
        f32x4 v = {1.f, 0.f, 0.f, 0.f};              // identity rotation
        if (p <= t && p + t <= 508) {                // active op at (t,p)
            int L = (t - p) >> 1;                    // layer 0..254
            int k = ((L * (511 - L)) >> 1) + p;      // off(L) = L*(511-L)/2
            float st, ct, sp, cp;
            __sincosf(theta[k], &st, &ct);
            __sincosf(phi[k], &sp, &cp);
            v = (f32x4){ct, st * cp, st * sp, 0.f};
        }
        cf3[(g * 16 + 8 * s + jj) * 64 + l] = v;
    }
}

// ---------------- build U columns ----------------
__device__ __forceinline__ float dpp_up1(float x) {   // lane i <- lane i-1, lane0 -> 0
    int r = __builtin_amdgcn_update_dpp(0, __builtin_bit_cast(int, x), 0x138, 0xF, 0xF, true);
    return __builtin_bit_cast(float, r);
}
__device__ __forceinline__ float dpp_dn1(float x) {   // lane i <- lane i+1, lane63 -> 0
    int r = __builtin_amdgcn_update_dpp(0, __builtin_bit_cast(int, x), 0x130, 0xF, 0xF, true);
    return __builtin_bit_cast(float, r);
}

__device__ __forceinline__ void rot2(float& ar, float& ai, float& br, float& bi, f32x4 co) {
    float c = co.x, sx = co.y, sy = co.z;
    float nar = c * ar - (sx * br + sy * bi);
    float nai = c * ai - (sx * bi - sy * br);
    float nbr = sx * ar - sy * ai + c * br;
    float nbi = sx * ai + sy * ar + c * bi;
    ar = nar; ai = nai; br = nbr; bi = nbi;
}

__global__ __launch_bounds__(128, 1) void build_kernel(const f32x4* __restrict__ cf3,
                                                       const float* __restrict__ phi_ext,
                                                       float* __restrict__ Wt) {
    // ring: 3 groups x 16 slots x 64 lanes x 16B = 49,152 B
    __shared__ f32x4 ring[3 * 16 * 64];

    const int j   = blockIdx.x;          // column of U
    const int tid = threadIdx.x;
    const int wid = tid >> 6;            // 0 = consumer wave, 1 = producer wave
    const int l   = tid & 63;
    const int r0  = 4 * l;

    // consumer state (rows 4l..4l+3 of column j), unused by producer lanes
    float ur0 = (r0 + 0 == j) ? 1.f : 0.f, ui0 = 0.f;
    float ur1 = (r0 + 1 == j) ? 1.f : 0.f, ui1 = 0.f;
    float ur2 = (r0 + 2 == j) ? 1.f : 0.f, ui2 = 0.f;
    float ur3 = (r0 + 3 == j) ? 1.f : 0.f, ui3 = 0.f;
    const float lane0_one = (l == 0) ? 1.f : 0.f;   // fix C.x at lane 0 (identity)

    // producer: load group g (16 x dwordx4) then write into ring slot
    auto produce = [&](int g, int slot) {
        const f32x4* sp = cf3 + (size_t)g * 1024 + l;
        f32x4* dp = ring + slot * 1024 + l;
        f32x4 T[16];
#pragma unroll
        for (int s = 0; s < 16; ++s) T[s] = sp[s * 64];
#pragma unroll
        for (int s = 0; s < 16; ++s) dp[s * 64] = T[s];
    };

    // consumer: 8 steps from ring slot (reads LDS only)
    auto compute = [&](int slot) {
        const f32x4* rp = ring + slot * 1024 + l;
        f32x4 R[16];
#pragma unroll
        for (int s = 0; s < 16; ++s) R[s] = rp[s * 64];
#pragma unroll
        for (int jj = 0; jj < 8; ++jj) {
            if ((jj & 1) == 0) {
                // even step: p=4l (rows 4l,4l+1), p=4l+2 (rows 4l+2,4l+3), intra-lane
                rot2(ur0, ui0, ur1, ui1, R[jj]);
                rot2(ur2, ui2, ur3, ui3, R[8 + jj]);
            } else {
                // DPP reads pre-step neighbor state (lockstep, before any write)
                float d0r = dpp_dn1(ur0), d0i = dpp_dn1(ui0);  // lane l+1's row 4l+4
                float u3r = dpp_up1(ur3), u3i = dpp_up1(ui3);  // lane l-1's row 4l-1
                f32x4 cb = R[8 + jj];
                // C coeffs (p = 4l-1) = lane l-1's B; lane0 -> identity via +1 on x
                float cx = dpp_up1(cb.x) + lane0_one;
                float cy = dpp_up1(cb.y);
                float cz = dpp_up1(cb.z);
                // p = 4l+1: rows 4l+1,4l+2 intra-lane
                rot2(ur1, ui1, ur2, ui2, R[jj]);
                // p = 4l+3: upper row here; partner from lane l+1 (lane63: B=identity)
                float n3r = cb.x * ur3 - (cb.y * d0r + cb.z * d0i);
                float n3i = cb.x * ui3 - (cb.y * d0i - cb.z * d0r);
                // p = 4l-1: lower row here; upper row from lane l-1 (lane0: identity)
                float n0r = cy * u3r - cz * u3i + cx * ur0;
                float n0i = cy * u3i + cz * u3r + cx * ui0;
                ur3 = n3r; ui3 = n3i; ur0 = n0r; ui0 = n0i;
            }
        }
    };

    // prefill: producer stages groups 0,1
    if (wid == 1) {
        produce(0, 0);
        produce(1, 1);
    }
    __syncthreads();

    int rslot = 0, wslot = 2;
    for (int grp = 0; grp < 64; ++grp) {
        if (wid == 0) {
            compute(rslot);                 // group grp (ds_read + VALU only)
        } else {
            int g = grp + 2;
            if (g < 64) produce(g, wslot);  // 2 barrier-intervals ahead of consumption
        }
        __syncthreads();
        rslot = (rslot == 2) ? 0 : rslot + 1;
        wslot = (wslot == 2) ? 0 : wslot + 1;
    }

    // phase screen + real part; store transposed (Wt[j][i]) for coalesced GEMM reads
    if (wid == 0) {
        float4 pe = *(const float4*)(phi_ext + r0);
        float s0, c0s, s1, c1s, s2, c2s, s3, c3s;
        __sincosf(pe.x, &s0, &c0s);
        __sincosf(pe.y, &s1, &c1s);
        __sincosf(pe.z, &s2, &c2s);
        __sincosf(pe.w, &s3, &c3s);
        float w0 = c0s * ur0 - s0 * ui0;
        float w1 = c1s * ur1 - s1 * ui1;
        float w2 = c2s * ur2 - s2 * ui2;
        float w3 = c3s * ur3 - s3 * ui3;
        *(float4*)(Wt + j * NN + r0) = make_float4(w0, w1, w2, w3);
    }
}

// ---------------- out = x @ Wt (fp32; no fp32 MFMA on CDNA4) ----------------
__global__ __launch_bounds__(256) void gemm_kernel(const float* __restrict__ x,
                                                   const float* __restrict__ Wt,
                                                   float* __restrict__ out) {
    __shared__ float Xs[64][36];
    __shared__ float Bs[32][68];

    const int tid = threadIdx.x;
    const int b0 = blockIdx.x * 64;
    const int i0 = blockIdx.y * 64;
    const int tx = tid & 15;
    const int ty = tid >> 4;

    const int xr = tid >> 3;
    const int xc = (tid & 7) * 4;
    const int bk = tid >> 4;
    const int bc = (tid & 15) * 4;

    float acc[4][4] = {};

    for (int k0 = 0; k0 < NN; k0 += 32) {
        float4 g0 = *(const float4*)(x + (b0 + xr) * NN + k0 + xc);
        float4 g1 = *(const float4*)(x + (b0 + xr + 32) * NN + k0 + xc);
        float4 w0 = *(const float4*)(Wt + (k0 + bk) * NN + i0 + bc);
        float4 w1 = *(const float4*)(Wt + (k0 + bk + 16) * NN + i0 + bc);
        *(float4*)&Xs[xr][xc]      = g0;
        *(float4*)&Xs[xr + 32][xc] = g1;
        *(float4*)&Bs[bk][bc]      = w0;
        *(float4*)&Bs[bk + 16][bc] = w1;
        __syncthreads();

#pragma unroll 8
        for (int k = 0; k < 32; ++k) {
            float4 bv = *(const float4*)&Bs[k][tx * 4];
            float x0 = Xs[ty * 4 + 0][k];
            float x1 = Xs[ty * 4 + 1][k];
            float x2 = Xs[ty * 4 + 2][k];
            float x3 = Xs[ty * 4 + 3][k];
            acc[0][0] += x0 * bv.x; acc[0][1] += x0 * bv.y; acc[0][2] += x0 * bv.z; acc[0][3] += x0 * bv.w;
            acc[1][0] += x1 * bv.x; acc[1][1] += x1 * bv.y; acc[1][2] += x1 * bv.z; acc[1][3] += x1 * bv.w;
            acc[2][0] += x2 * bv.x; acc[2][1] += x2 * bv.y; acc[2][2] += x2 * bv.z; acc[2][3] += x2 * bv.w;
            acc[3][0] += x3 * bv.x; acc[3][1] += x3 * bv.y; acc[3][2] += x3 * bv.z; acc[3][3] += x3 * bv.w;
        }
        __syncthreads();
    }

#pragma unroll
    for (int mm = 0; mm < 4; ++mm) {
        *(float4*)(out + (b0 + ty * 4 + mm) * NN + i0 + tx * 4) =
            make_float4(acc[mm][0], acc[mm][1], acc[mm][2], acc[mm][3]);
    }
}

extern "C" void kernel_launch(void* const* d_in, const int* in_sizes, int n_in,
                              void* d_out, int out_size, void* d_ws, size_t ws_size,
                              hipStream_t stream) {
    const float* x     = (const float*)d_in[0];
    const float* theta = (const float*)d_in[1];
    const float* phi_i = (const float*)d_in[2];
    const float* phi_e = (const float*)d_in[3];
    float* out = (float*)d_out;

    f32x4* cf3 = (f32x4*)d_ws;                         // 64*16*64*16 = 1,048,576 B
    float* Wt  = (float*)((char*)d_ws + WS_WT_OFF);    // 256*256*4   =   262,144 B

    coeff2_kernel<<<dim3(512), dim3(64), 0, stream>>>(theta, phi_i, cf3);
    build_kernel<<<dim3(NN), dim3(128), 0, stream>>>(cf3, phi_e, Wt);
    gemm_kernel<<<dim3(NB / 64, NN / 64), dim3(256), 0, stream>>>(x, Wt, out);
}

// Round 6
// 73.338 us; speedup vs baseline: 1.3424x; 1.0467x over previous
//
#include <hip/hip_runtime.h>

// Reck-mesh MZI layer, N=256, BATCH=4096.
// out[b][i] = sum_j x[b][j] * Re(e^{i phi_ext[i]} U[i][j])
// Wavefront schedule t = 2L + p (depth 509, padded 512): ops at equal t touch
// disjoint row pairs. One consumer wave per column; lane l holds rows 4l..4l+3.
// Block = 2 waves. Producer pipeline (T14 split-phase, K=4 LDS ring):
//   interval k: ds_write group k+2 (loaded 2 intervals ago -> vmcnt free),
//               issue loads for group k+4 (2-interval lead).
// Consumer: prefetch-read group k+1 from ring, compute group k from registers.
// Ping-pong register buffers, loop unrolled x2 -> all static indices.

#define NN 256
#define NB 4096
// table: 64 groups x 16 slots x 64 lanes x 16B = 1,048,576 B
#define WS_WT_OFF 1048576           // Wt[256][256] after the table

typedef float f32x4 __attribute__((ext_vector_type(4)));

// ---------------- coefficient stream ----------------
// t = 8g + jj. slot A_jj = jj (p = 4l, +1 if t odd), slot B_jj = 8+jj (p = A+2).
// Identity (1,0,0) baked in for inactive ops.
__global__ __launch_bounds__(64) void coeff2_kernel(const float* __restrict__ theta,
                                                    const float* __restrict__ phi,
                                                    f32x4* __restrict__ cf3) {
    const int t = blockIdx.x;        // 0..511
    const int l = threadIdx.x;
    const int g = t >> 3, jj = t & 7;
    const int pA = (t & 1) ? (4 * l + 1) : (4 * l);
#pragma unroll
    for (int s = 0; s < 2; ++s) {
        int p = pA + 2 * s;
        f32x4 v = {1.f, 0.f, 0.f, 0.f};              // identity rotation
        if (p <= t && p + t <= 508) {                // active op at (t,p)
            int L = (t - p) >> 1;                    // layer 0..254
            int k = ((L * (511 - L)) >> 1) + p;      // off(L) = L*(511-L)/2
            float st, ct, sp, cp;
            __sincosf(theta[k], &st, &ct);
            __sincosf(phi[k], &sp, &cp);
            v = (f32x4){ct, st * cp, st * sp, 0.f};
        }
        cf3[(g * 16 + 8 * s + jj) * 64 + l] = v;
    }
}

// ---------------- build U columns ----------------
__device__ __forceinline__ float dpp_up1(float x) {   // lane i <- lane i-1, lane0 -> 0
    int r = __builtin_amdgcn_update_dpp(0, __builtin_bit_cast(int, x), 0x138, 0xF, 0xF, true);
    return __builtin_bit_cast(float, r);
}
__device__ __forceinline__ float dpp_dn1(float x) {   // lane i <- lane i+1, lane63 -> 0
    int r = __builtin_amdgcn_update_dpp(0, __builtin_bit_cast(int, x), 0x130, 0xF, 0xF, true);
    return __builtin_bit_cast(float, r);
}

__device__ __forceinline__ void rot2(float& ar, float& ai, float& br, float& bi, f32x4 co) {
    float c = co.x, sx = co.y, sy = co.z;
    float nar = c * ar - (sx * br + sy * bi);
    float nai = c * ai - (sx * bi - sy * br);
    float nbr = sx * ar - sy * ai + c * br;
    float nbi = sx * ai + sy * ar + c * bi;
    ar = nar; ai = nai; br = nbr; bi = nbi;
}

__global__ __launch_bounds__(128, 1) void build_kernel(const f32x4* __restrict__ cf3,
                                                       const float* __restrict__ phi_ext,
                                                       float* __restrict__ Wt) {
    // ring: 4 groups x 16 slots x 64 lanes x 16B = 65,536 B
    __shared__ f32x4 ring[4 * 16 * 64];

    const int j   = blockIdx.x;          // column of U
    const int tid = threadIdx.x;
    const int wid = tid >> 6;            // 0 = consumer wave, 1 = producer wave
    const int l   = tid & 63;
    const int r0  = 4 * l;

    // consumer state (rows 4l..4l+3 of column j), unused by producer lanes
    float ur0 = (r0 + 0 == j) ? 1.f : 0.f, ui0 = 0.f;
    float ur1 = (r0 + 1 == j) ? 1.f : 0.f, ui1 = 0.f;
    float ur2 = (r0 + 2 == j) ? 1.f : 0.f, ui2 = 0.f;
    float ur3 = (r0 + 3 == j) ? 1.f : 0.f, ui3 = 0.f;
    const float lane0_one = (l == 0) ? 1.f : 0.f;   // fix C.x at lane 0 (identity)

    f32x4 TA[16], TB[16];   // producer ping-pong (global -> reg)
    f32x4 RA[16], RB[16];   // consumer ping-pong (LDS -> reg)

    auto loadgrp = [&](int g, f32x4 (&T)[16]) {
        const f32x4* sp = cf3 + (size_t)g * 1024 + l;
#pragma unroll
        for (int s = 0; s < 16; ++s) T[s] = sp[s * 64];
    };
    auto writeslot = [&](int slot, const f32x4 (&T)[16]) {
        f32x4* dp = ring + slot * 1024 + l;
#pragma unroll
        for (int s = 0; s < 16; ++s) dp[s * 64] = T[s];
    };
    auto readslot = [&](int slot, f32x4 (&R)[16]) {
        const f32x4* rp = ring + slot * 1024 + l;
#pragma unroll
        for (int s = 0; s < 16; ++s) R[s] = rp[s * 64];
    };

    // consumer: 8 steps from register buffer R (VALU + DPP only)
    auto compute = [&](const f32x4 (&R)[16]) {
#pragma unroll
        for (int jj = 0; jj < 8; ++jj) {
            if ((jj & 1) == 0) {
                // even step: p=4l (rows 4l,4l+1), p=4l+2 (rows 4l+2,4l+3), intra-lane
                rot2(ur0, ui0, ur1, ui1, R[jj]);
                rot2(ur2, ui2, ur3, ui3, R[8 + jj]);
            } else {
                // DPP reads pre-step neighbor state (lockstep, before any write)
                float d0r = dpp_dn1(ur0), d0i = dpp_dn1(ui0);  // lane l+1's row 4l+4
                float u3r = dpp_up1(ur3), u3i = dpp_up1(ui3);  // lane l-1's row 4l-1
                f32x4 cb = R[8 + jj];
                // C coeffs (p = 4l-1) = lane l-1's B; lane0 -> identity via +1 on x
                float cx = dpp_up1(cb.x) + lane0_one;
                float cy = dpp_up1(cb.y);
                float cz = dpp_up1(cb.z);
                // p = 4l+1: rows 4l+1,4l+2 intra-lane
                rot2(ur1, ui1, ur2, ui2, R[jj]);
                // p = 4l+3: upper row here; partner from lane l+1 (lane63: B=identity)
                float n3r = cb.x * ur3 - (cb.y * d0r + cb.z * d0i);
                float n3i = cb.x * ui3 - (cb.y * d0i - cb.z * d0r);
                // p = 4l-1: lower row here; upper row from lane l-1 (lane0: identity)
                float n0r = cy * u3r - cz * u3i + cx * ur0;
                float n0i = cy * u3i + cz * u3r + cx * ui0;
                ur3 = n3r; ui3 = n3i; ur0 = n0r; ui0 = n0i;
            }
        }
    };

    // ---- prefill: producer stages groups 0,1 into slots 0,1; holds 2,3 in regs
    if (wid == 1) {
        loadgrp(0, TA);
        loadgrp(1, TB);
        writeslot(0, TA);
        loadgrp(2, TA);      // written at interval 0
        writeslot(1, TB);
        loadgrp(3, TB);      // written at interval 1
    }
    __syncthreads();
    if (wid == 0) readslot(0, RA);   // pre-read group 0 (slot 0 synced above)

    // ---- 64 intervals, unrolled x2 for static ping-pong
    for (int g2 = 0; g2 < 64; g2 += 2) {
        // interval g2: compute group g2 (RA); prefetch group g2+1 -> RB
        if (wid == 0) {
            if (g2 + 1 < 64) readslot((g2 + 1) & 3, RB);
            compute(RA);
        } else {
            if (g2 + 2 < 64) writeslot((g2 + 2) & 3, TA);  // loaded 2 intervals ago
            if (g2 + 4 < 64) loadgrp(g2 + 4, TA);          // 2-interval lead
        }
        __syncthreads();
        // interval g2+1: compute group g2+1 (RB); prefetch group g2+2 -> RA
        if (wid == 0) {
            if (g2 + 2 < 64) readslot((g2 + 2) & 3, RA);
            compute(RB);
        } else {
            if (g2 + 3 < 64) writeslot((g2 + 3) & 3, TB);
            if (g2 + 5 < 64) loadgrp(g2 + 5, TB);
        }
        __syncthreads();
    }

    // phase screen + real part; store transposed (Wt[j][i]) for coalesced GEMM reads
    if (wid == 0) {
        float4 pe = *(const float4*)(phi_ext + r0);
        float s0, c0s, s1, c1s, s2, c2s, s3, c3s;
        __sincosf(pe.x, &s0, &c0s);
        __sincosf(pe.y, &s1, &c1s);
        __sincosf(pe.z, &s2, &c2s);
        __sincosf(pe.w, &s3, &c3s);
        float w0 = c0s * ur0 - s0 * ui0;
        float w1 = c1s * ur1 - s1 * ui1;
        float w2 = c2s * ur2 - s2 * ui2;
        float w3 = c3s * ur3 - s3 * ui3;
        *(float4*)(Wt + j * NN + r0) = make_float4(w0, w1, w2, w3);
    }
}

// ---------------- out = x @ Wt (fp32; no fp32 MFMA on CDNA4) ----------------
__global__ __launch_bounds__(256) void gemm_kernel(const float* __restrict__ x,
                                                   const float* __restrict__ Wt,
                                                   float* __restrict__ out) {
    __shared__ float Xs[64][36];
    __shared__ float Bs[32][68];

    const int tid = threadIdx.x;
    const int b0 = blockIdx.x * 64;
    const int i0 = blockIdx.y * 64;
    const int tx = tid & 15;
    const int ty = tid >> 4;

    const int xr = tid >> 3;
    const int xc = (tid & 7) * 4;
    const int bk = tid >> 4;
    const int bc = (tid & 15) * 4;

    float acc[4][4] = {};

    for (int k0 = 0; k0 < NN; k0 += 32) {
        float4 g0 = *(const float4*)(x + (b0 + xr) * NN + k0 + xc);
        float4 g1 = *(const float4*)(x + (b0 + xr + 32) * NN + k0 + xc);
        float4 w0 = *(const float4*)(Wt + (k0 + bk) * NN + i0 + bc);
        float4 w1 = *(const float4*)(Wt + (k0 + bk + 16) * NN + i0 + bc);
        *(float4*)&Xs[xr][xc]      = g0;
        *(float4*)&Xs[xr + 32][xc] = g1;
        *(float4*)&Bs[bk][bc]      = w0;
        *(float4*)&Bs[bk + 16][bc] = w1;
        __syncthreads();

#pragma unroll 8
        for (int k = 0; k < 32; ++k) {
            float4 bv = *(const float4*)&Bs[k][tx * 4];
            float x0 = Xs[ty * 4 + 0][k];
            float x1 = Xs[ty * 4 + 1][k];
            float x2 = Xs[ty * 4 + 2][k];
            float x3 = Xs[ty * 4 + 3][k];
            acc[0][0] += x0 * bv.x; acc[0][1] += x0 * bv.y; acc[0][2] += x0 * bv.z; acc[0][3] += x0 * bv.w;
            acc[1][0] += x1 * bv.x; acc[1][1] += x1 * bv.y; acc[1][2] += x1 * bv.z; acc[1][3] += x1 * bv.w;
            acc[2][0] += x2 * bv.x; acc[2][1] += x2 * bv.y; acc[2][2] += x2 * bv.z; acc[2][3] += x2 * bv.w;
            acc[3][0] += x3 * bv.x; acc[3][1] += x3 * bv.y; acc[3][2] += x3 * bv.z; acc[3][3] += x3 * bv.w;
        }
        __syncthreads();
    }

#pragma unroll
    for (int mm = 0; mm < 4; ++mm) {
        *(float4*)(out + (b0 + ty * 4 + mm) * NN + i0 + tx * 4) =
            make_float4(acc[mm][0], acc[mm][1], acc[mm][2], acc[mm][3]);
    }
}

extern "C" void kernel_launch(void* const* d_in, const int* in_sizes, int n_in,
                              void* d_out, int out_size, void* d_ws, size_t ws_size,
                              hipStream_t stream) {
    const float* x     = (const float*)d_in[0];
    const float* theta = (const float*)d_in[1];
    const float* phi_i = (const float*)d_in[2];
    const float* phi_e = (const float*)d_in[3];
    float* out = (float*)d_out;

    f32x4* cf3 = (f32x4*)d_ws;                         // 64*16*64*16 = 1,048,576 B
    float* Wt  = (float*)((char*)d_ws + WS_WT_OFF);    // 256*256*4   =   262,144 B

    coeff2_kernel<<<dim3(512), dim3(64), 0, stream>>>(theta, phi_i, cf3);
    build_kernel<<<dim3(NN), dim3(128), 0, stream>>>(cf3, phi_e, Wt);
    gemm_kernel<<<dim3(NB / 64, NN / 64), dim3(256), 0, stream>>>(x, Wt, out);
}